// Round 3
// baseline (794.036 us; speedup 1.0000x reference)
//
#include <hip/hip_runtime.h>
#include <stdint.h>
#include <stddef.h>

typedef __bf16 bf16;
typedef __bf16 bf16x4 __attribute__((ext_vector_type(4)));
typedef __bf16 bf16x8 __attribute__((ext_vector_type(8)));
typedef float f32x4 __attribute__((ext_vector_type(4)));
typedef float f32x16 __attribute__((ext_vector_type(16)));

#define BNI 0.9999950000374996f  // 1/sqrt(1+1e-5)
#define NROW 120                  // valid rows per block (6 polylines x 20)
#define NPOLYB 6
#define TOTROW 163840
#define NPOLY 8192
#define NBLK 1366                 // ceil(163840/120)

// swizzled act addressing: row-major stride 256 bf16, 16B chunks XOR-swizzled by row
#define AADDR(r, ch) ((r)*256 + ((((ch) ^ ((r)&31)))<<3))

// dynamic LDS layout (bytes) — 80920 B/block => 2 blocks/CU (161840 <= 163840)
#define OFF_ACT  0                // 120*512 = 61440 (sAct; rows 0..5 reused as sY)
#define OFF_WB0  61440            // 8192: weight chunk buf0 (aliased by sPool)
#define OFF_WB1  69632            // 8192: weight chunk buf1
#define OFF_T2   77824            // 6*256*2 = 3072 (t2, bf16)
#define OFF_VAL  80896            // 6*4 = 24
#define LDS_TOTAL 80920

// ws layout (bf16 elems) — BN-folded weights
#define WS_PRE_W0 0
#define WS_PRE_W1 8192
#define WS_PRE_W2 73728
#define WS_MLP_W0 139264
#define WS_MLP_W1 270336
#define WS_MLP_W2 335872
#define WS_OUT_W0 401408
#define WS_OUT_W1 466944

__device__ __forceinline__ bf16 f2b(float f){
  unsigned int i = __builtin_bit_cast(unsigned int, f);
  unsigned int r = i + 0x7fffu + ((i >> 16) & 1u);
  unsigned short h = (unsigned short)(r >> 16);
  return __builtin_bit_cast(bf16, h);
}
__device__ __forceinline__ float b2f(bf16 x){
  unsigned short u = __builtin_bit_cast(unsigned short, x);
  union { unsigned int i; float f; } v; v.i = ((unsigned int)u) << 16; return v.f;
}
__device__ __forceinline__ bf16x8 ld8f(const float* p, float sc){
  f32x4 a = *(const f32x4*)p;
  f32x4 b = *(const f32x4*)(p + 4);
  bf16x8 r;
  #pragma unroll
  for (int j = 0; j < 4; ++j){ r[j] = f2b(a[j]*sc); r[4+j] = f2b(b[j]*sc); }
  return r;
}

// ---------------- prep: fp32 weights -> bf16 in ws, BN scale folded ----------------
__global__ __launch_bounds__(256)
void prep_kernel(const float* s0, const float* s1, const float* s2, const float* s3,
                 const float* s4, const float* s5, const float* s6, const float* s7,
                 const float* g0, const float* g1, const float* g3, const float* g4,
                 bf16* dst)
{
  const int offs[8] = {WS_PRE_W0, WS_PRE_W1, WS_PRE_W2, WS_MLP_W0,
                       WS_MLP_W1, WS_MLP_W2, WS_OUT_W0, WS_OUT_W1};
  const int sz[8]   = {8192, 65536, 65536, 131072, 65536, 65536, 65536, 65536};
  const int ld[8]   = {32, 256, 256, 512, 256, 256, 256, 256};
  int r = blockIdx.y;
  const float* src = s0;
  if (r == 1) src = s1; else if (r == 2) src = s2; else if (r == 3) src = s3;
  else if (r == 4) src = s4; else if (r == 5) src = s5; else if (r == 6) src = s6;
  else if (r == 7) src = s7;
  const float* gp = (r==0)?g0:(r==1)?g1:(r==3)?g3:(r==4)?g4:nullptr;
  int i = (blockIdx.x*256 + threadIdx.x)*8;
  if (i < sz[r]){
    float sc = gp ? gp[i/ld[r]]*BNI : 1.0f;   // i..i+7 same row (ld % 8 == 0)
    *(bf16x8*)&dst[offs[r] + i] = ld8f(src + i, sc);
  }
}

// ---- stage one half-K chunk (32 feats x 128 k = 8 KB): global->regs->LDS swizzled
// chunk c: nt = c>>1 (feature tile), kh = c&1 (K half)
__device__ __forceinline__ void stageLoadK(bf16x8* st, const bf16* W, int ldK, int c, int tid){
  int nt = c >> 1, kh = c & 1;
  #pragma unroll
  for (int i = 0; i < 2; ++i){
    int id = tid + 256*i;               // 512 16B-chunks
    int fr = id >> 4, kc = id & 15;
    st[i] = *(const bf16x8*)(W + (size_t)(nt*32 + fr)*ldK + kh*128 + kc*8);
  }
}
__device__ __forceinline__ void stageStoreK(const bf16x8* st, bf16* buf, int tid){
  #pragma unroll
  for (int i = 0; i < 2; ++i){
    int id = tid + 256*i;
    int fr = id >> 4, kc = id & 15;
    *(bf16x8*)&buf[fr*128 + ((kc ^ (fr & 15))<<3)] = st[i];
  }
}

// transposed epilogue: lane owns act-row `row`; 4 consecutive features per quad
template<int RELU, int MASK, int ADDT2>
__device__ __forceinline__ void epiT(
    const f32x16& acc, int nt, int row, int poly, float mk, bool valid,
    bf16* sAct, const bf16* sT2, const float* bptr, int hi)
{
  #pragma unroll
  for (int q2 = 0; q2 < 4; ++q2){
    int f0 = nt*32 + 8*q2 + 4*hi;
    f32x4 bb = *(const f32x4*)(bptr + f0);
    bf16x4 tv = {};
    if (ADDT2) tv = *(const bf16x4*)&sT2[poly*256 + f0];
    bf16x4 o;
    #pragma unroll
    for (int j = 0; j < 4; ++j){
      float v = acc[4*q2 + j];
      if (ADDT2) v += b2f(tv[j]);
      v += bb[j];
      if (RELU) v = fmaxf(v, 0.0f);
      if (MASK) v *= mk;
      o[j] = f2b(v);
    }
    if (valid)
      *(bf16x4*)&sAct[row*256 + (((nt*4 + q2) ^ (row & 31))<<3) + 4*hi] = o;
  }
}

// 256->256 layer: LDS-staged dbuf 8KB weight chunks (1 barrier/chunk), transposed MFMA
// 16 chunks = 8 feature tiles x 2 K-halves; acc carried across each K-half pair
template<int RELU, int MASK, int ADDT2>
__device__ __forceinline__ void layerT(
    bf16* sAct, bf16* wb0, bf16* wb1, const bf16* sT2,
    const bf16* W, int ldK, const float* bptr,
    const int* maskp, int blk, int row, int rowc, int lane32, int hi, int tid)
{
  bf16x8 B[16];
  #pragma unroll
  for (int t = 0; t < 16; ++t)
    B[t] = *(const bf16x8*)&sAct[AADDR(rowc, 2*t + hi)];   // own-row, intra-wave dep

  float mk = 1.0f;
  if (MASK){
    int g = blk*NROW + row;
    mk = (row < NROW && g < TOTROW && maskp[g]) ? 1.0f : 0.0f;
  }
  const int poly = rowc/20;
  const bool valid = row < NROW;

  bf16x8 st[2];
  stageLoadK(st, W, ldK, 0, tid);
  stageStoreK(st, wb0, tid);
  __syncthreads();                       // chunk 0 staged (entry barrier also protects wb reuse)
  f32x16 acc;
  #pragma unroll 1
  for (int c = 0; c < 16; ++c){
    const bf16* cur = (c & 1) ? wb1 : wb0;
    bf16* nxt = (c & 1) ? wb0 : wb1;
    if (c < 15) stageLoadK(st, W, ldK, c + 1, tid);   // global loads under compute
    const int kh = c & 1;
    bf16x8 wf[8];
    const bf16* base = cur + lane32*128;
    #pragma unroll
    for (int t = 0; t < 8; ++t)
      wf[t] = *(const bf16x8*)(base + (((2*t + hi) ^ (lane32 & 15))<<3));
    if (kh == 0){
      #pragma unroll
      for (int j = 0; j < 16; ++j) acc[j] = 0.0f;
    }
    #pragma unroll
    for (int t = 0; t < 8; ++t)
      acc = __builtin_amdgcn_mfma_f32_32x32x16_bf16(wf[t], B[8*kh + t], acc, 0, 0, 0);
    if (kh == 1)
      epiT<RELU,MASK,ADDT2>(acc, c >> 1, row, poly, mk, valid, sAct, sT2, bptr, hi);
    if (c < 15) stageStoreK(st, nxt, tid);            // other buffer: WAR-safe post-barrier(c-1)
    __syncthreads();                                  // chunk c+1 staged AND compute c done
  }
}

// pool 20 mask-zeroed rows per polyline -> sPool rows 0..5 (swizzled)
__device__ __forceinline__ void poolT(const bf16* sAct, bf16* sPool, int tid){
  if (tid < 192){
    int poly = tid >> 5, c = tid & 31;
    float m[8];
    bf16x8 v0 = *(const bf16x8*)&sAct[AADDR(poly*20, c)];
    #pragma unroll
    for (int j = 0; j < 8; ++j) m[j] = b2f(v0[j]);
    for (int r = 1; r < 20; ++r){
      bf16x8 v = *(const bf16x8*)&sAct[AADDR(poly*20 + r, c)];
      #pragma unroll
      for (int j = 0; j < 8; ++j) m[j] = fmaxf(m[j], b2f(v[j]));
    }
    bf16x8 o;
    #pragma unroll
    for (int j = 0; j < 8; ++j) o[j] = f2b(m[j]);
    *(bf16x8*)&sPool[AADDR(poly, c)] = o;
  }
}

__global__ __launch_bounds__(256, 2)
void traj_kernel(const float* __restrict__ poly, const int* __restrict__ maskp,
                 const float* pre_b0, const float* pre_b1, const float* pre_bias2,
                 const float* mlp_b0, const float* mlp_b1, const float* mlp_bias2,
                 const float* out_b0, const float* out_b1,
                 const bf16* __restrict__ ws,
                 float* __restrict__ outp)
{
  extern __shared__ char smem[];
  bf16*  sAct   = (bf16*)(smem + OFF_ACT);
  bf16*  wb0    = (bf16*)(smem + OFF_WB0);
  bf16*  wb1    = (bf16*)(smem + OFF_WB1);
  bf16*  sT2    = (bf16*)(smem + OFF_T2);
  float* sValid = (float*)(smem + OFF_VAL);
  bf16*  sPool  = wb0;                       // pooled tile aliases wb0 (barrier-separated)
  bf16*  sY     = sAct;                      // y tile aliases sAct (dead after pool2)

  const int tid = threadIdx.x;
  const int w = tid >> 6, L = tid & 63, lane32 = L & 31, hi = L >> 5;
  const int row  = w*32 + lane32;            // 0..127; valid < 120
  const int rowc = row < NROW ? row : NROW - 1;
  const int blk = blockIdx.x;

  const bf16* pw0 = ws + WS_PRE_W0;
  const bf16* pw1 = ws + WS_PRE_W1;
  const bf16* pw2 = ws + WS_PRE_W2;
  const bf16* mw0 = ws + WS_MLP_W0;
  const bf16* mw1 = ws + WS_MLP_W1;
  const bf16* mw2 = ws + WS_MLP_W2;
  const bf16* ow0 = ws + WS_OUT_W0;
  const bf16* ow1 = ws + WS_OUT_W1;

  // ---- phase 0: input (120x32 fp32 -> bf16, swizzled; OOB rows zero) ----
  #pragma unroll
  for (int i = 0; i < 2; ++i){
    int id = tid + 256*i;
    if (id < 480){
      int r = id >> 2, c = id & 3;
      int grow = blk*NROW + r;
      bf16x8 v = {};
      if (grow < TOTROW) v = ld8f(poly + (size_t)grow*32 + c*8, 1.0f);
      *(bf16x8*)&sAct[AADDR(r, c)] = v;
    }
  }
  __syncthreads();
  if (tid < NPOLYB){
    float v = 0.0f;
    #pragma unroll
    for (int r = 0; r < 20; ++r){
      int g = blk*NROW + tid*20 + r;
      if (g < TOTROW && maskp[g]) v = 1.0f;
    }
    sValid[tid] = v;                         // consumed in out1 (after several barriers)
  }

  // ---- pre0: K=32, transposed, W direct from ws (tiny) ----
  {
    bf16x8 B0 = *(const bf16x8*)&sAct[AADDR(rowc, hi)];
    bf16x8 B1 = *(const bf16x8*)&sAct[AADDR(rowc, 2 + hi)];
    #pragma unroll 1
    for (int nt = 0; nt < 8; ++nt){
      const bf16* p = pw0 + (size_t)(nt*32 + lane32)*32 + 8*hi;
      bf16x8 w0 = *(const bf16x8*)p;
      bf16x8 w1 = *(const bf16x8*)(p + 16);
      f32x16 acc = {};
      acc = __builtin_amdgcn_mfma_f32_32x32x16_bf16(w0, B0, acc, 0, 0, 0);
      acc = __builtin_amdgcn_mfma_f32_32x32x16_bf16(w1, B1, acc, 0, 0, 0);
      epiT<1,0,0>(acc, nt, row, 0, 1.0f, row < NROW, sAct, sT2, pre_b0, hi);
    }
  }
  __syncthreads();      // pre0 done; wb buffers free for pre1 staging

  // ---- pre1, pre2 (LDS-staged dbuf) ----
  layerT<1,0,0>(sAct, wb0, wb1, sT2, pw1, 256, pre_b1,    maskp, blk, row, rowc, lane32, hi, tid);
  layerT<0,1,0>(sAct, wb0, wb1, sT2, pw2, 256, pre_bias2, maskp, blk, row, rowc, lane32, hi, tid);

  // last layer barrier done: all pre2 writes visible
  poolT(sAct, sPool, tid);
  __syncthreads();                    // pool1 visible

  // ---- t2 = pooled @ mlp_w0'[:,256:]^T : wave w handles nt = w, w+4 (direct global) ----
  {
    bf16x8 Bp[16];
    #pragma unroll
    for (int t = 0; t < 16; ++t)
      Bp[t] = *(const bf16x8*)&sPool[AADDR((lane32 < NPOLYB ? lane32 : 0), 2*t + hi)];
    #pragma unroll 1
    for (int it = 0; it < 2; ++it){
      int nt = w + 4*it;
      const bf16* p = mw0 + (size_t)(nt*32 + lane32)*512 + 256 + 8*hi;
      f32x16 acc = {};
      #pragma unroll
      for (int t = 0; t < 16; ++t){
        bf16x8 wf = *(const bf16x8*)(p + 16*t);
        acc = __builtin_amdgcn_mfma_f32_32x32x16_bf16(wf, Bp[t], acc, 0, 0, 0);
      }
      if (lane32 < NPOLYB){
        #pragma unroll
        for (int q2 = 0; q2 < 4; ++q2){
          int f0 = nt*32 + 8*q2 + 4*hi;
          bf16x4 o;
          #pragma unroll
          for (int j = 0; j < 4; ++j) o[j] = f2b(acc[4*q2 + j]);
          *(bf16x4*)&sT2[lane32*256 + f0] = o;
        }
      }
    }
  }
  __syncthreads();                    // sT2 ready; sPool(wb0) reads done

  // ---- mlp0 (x-half + t2), mlp1, mlp2 (LDS-staged dbuf) ----
  layerT<1,0,1>(sAct, wb0, wb1, sT2, mw0, 512, mlp_b0,    maskp, blk, row, rowc, lane32, hi, tid);
  layerT<1,0,0>(sAct, wb0, wb1, sT2, mw1, 256, mlp_b1,    maskp, blk, row, rowc, lane32, hi, tid);
  layerT<0,1,0>(sAct, wb0, wb1, sT2, mw2, 256, mlp_bias2, maskp, blk, row, rowc, lane32, hi, tid);

  // last layer barrier done
  poolT(sAct, sPool, tid);
  __syncthreads();                    // pool2 visible; sAct dead -> sY

  // ---- out0: y = relu(pool2 @ ow0^T + b0) -> sY rows 0..5; wave w: nt = w, w+4 ----
  {
    bf16x8 Bp[16];
    #pragma unroll
    for (int t = 0; t < 16; ++t)
      Bp[t] = *(const bf16x8*)&sPool[AADDR((lane32 < NPOLYB ? lane32 : 0), 2*t + hi)];
    #pragma unroll 1
    for (int it = 0; it < 2; ++it){
      int nt = w + 4*it;
      const bf16* p = ow0 + (size_t)(nt*32 + lane32)*256 + 8*hi;
      f32x16 acc = {};
      #pragma unroll
      for (int t = 0; t < 16; ++t){
        bf16x8 wf = *(const bf16x8*)(p + 16*t);
        acc = __builtin_amdgcn_mfma_f32_32x32x16_bf16(wf, Bp[t], acc, 0, 0, 0);
      }
      if (lane32 < NPOLYB){
        #pragma unroll
        for (int q2 = 0; q2 < 4; ++q2){
          int f0 = nt*32 + 8*q2 + 4*hi;
          f32x4 bb = *(const f32x4*)(out_b0 + f0);
          bf16x4 o;
          #pragma unroll
          for (int j = 0; j < 4; ++j) o[j] = f2b(fmaxf(acc[4*q2 + j] + bb[j], 0.0f));
          *(bf16x4*)&sY[lane32*256 + (((nt*4 + q2) ^ (lane32 & 31))<<3) + 4*hi] = o;
        }
      }
    }
  }
  __syncthreads();                    // y visible

  // ---- out1: z = (y @ ow1^T + b1) * valid -> global fp32; wave w: nt = w, w+4 ----
  {
    bf16x8 By[16];
    #pragma unroll
    for (int t = 0; t < 16; ++t)
      By[t] = *(const bf16x8*)&sY[AADDR((lane32 < NPOLYB ? lane32 : 0), 2*t + hi)];
    int gp = blk*NPOLYB + lane32;
    float vd = (lane32 < NPOLYB) ? sValid[lane32] : 0.0f;
    #pragma unroll 1
    for (int it = 0; it < 2; ++it){
      int nt = w + 4*it;
      const bf16* p = ow1 + (size_t)(nt*32 + lane32)*256 + 8*hi;
      f32x16 acc = {};
      #pragma unroll
      for (int t = 0; t < 16; ++t){
        bf16x8 wf = *(const bf16x8*)(p + 16*t);
        acc = __builtin_amdgcn_mfma_f32_32x32x16_bf16(wf, By[t], acc, 0, 0, 0);
      }
      if (lane32 < NPOLYB && gp < NPOLY){
        #pragma unroll
        for (int q2 = 0; q2 < 4; ++q2){
          int f0 = nt*32 + 8*q2 + 4*hi;
          f32x4 bb = *(const f32x4*)(out_b1 + f0);
          f32x4 o;
          #pragma unroll
          for (int j = 0; j < 4; ++j) o[j] = (acc[4*q2 + j] + bb[j]) * vd;
          *(f32x4*)&outp[(size_t)gp*256 + f0] = o;
        }
      }
    }
  }
}

extern "C" void kernel_launch(void* const* d_in, const int* in_sizes, int n_in,
                              void* d_out, int out_size, void* d_ws, size_t ws_size,
                              hipStream_t stream)
{
  const float* poly      = (const float*)d_in[0];
  const int*   maskp     = (const int*)  d_in[1];
  const float* pre_w0    = (const float*)d_in[2];
  const float* pre_g0    = (const float*)d_in[3];
  const float* pre_b0    = (const float*)d_in[4];
  const float* pre_w1    = (const float*)d_in[5];
  const float* pre_g1    = (const float*)d_in[6];
  const float* pre_b1    = (const float*)d_in[7];
  const float* pre_w2    = (const float*)d_in[8];
  const float* pre_bias2 = (const float*)d_in[9];
  const float* mlp_w0    = (const float*)d_in[10];
  const float* mlp_g0    = (const float*)d_in[11];
  const float* mlp_b0    = (const float*)d_in[12];
  const float* mlp_w1    = (const float*)d_in[13];
  const float* mlp_g1    = (const float*)d_in[14];
  const float* mlp_b1    = (const float*)d_in[15];
  const float* mlp_w2    = (const float*)d_in[16];
  const float* mlp_bias2 = (const float*)d_in[17];
  const float* out_w0    = (const float*)d_in[18];
  const float* out_b0    = (const float*)d_in[19];
  const float* out_w1    = (const float*)d_in[20];
  const float* out_b1    = (const float*)d_in[21];

  bf16* ws = (bf16*)d_ws;   // 1,064,960 B of ws used

  (void)hipFuncSetAttribute((const void*)&traj_kernel,
                            hipFuncAttributeMaxDynamicSharedMemorySize, LDS_TOTAL);

  prep_kernel<<<dim3(64, 8), dim3(256), 0, stream>>>(
      pre_w0, pre_w1, pre_w2, mlp_w0, mlp_w1, mlp_w2, out_w0, out_w1,
      pre_g0, pre_g1, mlp_g0, mlp_g1, ws);

  traj_kernel<<<dim3(NBLK), dim3(256), LDS_TOTAL, stream>>>(
      poly, maskp,
      pre_b0, pre_b1, pre_bias2,
      mlp_b0, mlp_b1, mlp_bias2,
      out_b0, out_b1,
      ws, (float*)d_out);
}

// Round 4
// 789.834 us; speedup vs baseline: 1.0053x; 1.0053x over previous
//
#include <hip/hip_runtime.h>
#include <stdint.h>
#include <stddef.h>

typedef __bf16 bf16;
typedef __bf16 bf16x4 __attribute__((ext_vector_type(4)));
typedef __bf16 bf16x8 __attribute__((ext_vector_type(8)));
typedef float f32x4 __attribute__((ext_vector_type(4)));
typedef float f32x16 __attribute__((ext_vector_type(16)));

#define BNI 0.9999950000374996f  // 1/sqrt(1+1e-5)
#define NROW 120                  // valid rows per block (6 polylines x 20)
#define NPOLYB 6
#define TOTROW 163840
#define NPOLY 8192
#define NBLK 1366                 // ceil(163840/120)

// swizzled act addressing: row-major stride 256 bf16, 16B chunks XOR-swizzled by row
#define AADDR(r, ch) ((r)*256 + ((((ch) ^ ((r)&31)))<<3))

// dynamic LDS layout (bytes) — 80920 B/block => 2 blocks/CU (161840 <= 163840)
#define OFF_ACT  0                // 120*512 = 61440 (sAct; rows 0..5 reused as sY)
#define OFF_WB0  61440            // 8192: weight chunk buf0 (aliased by sPool)
#define OFF_WB1  69632            // 8192: weight chunk buf1
#define OFF_T2   77824            // 6*256*2 = 3072 (t2, bf16)
#define OFF_VAL  80896            // 6*4 = 24
#define LDS_TOTAL 80920

// ws layout (bf16 elems) — BN-folded weights
#define WS_PRE_W0 0
#define WS_PRE_W1 8192
#define WS_PRE_W2 73728
#define WS_MLP_W0 139264
#define WS_MLP_W1 270336
#define WS_MLP_W2 335872
#define WS_OUT_W0 401408
#define WS_OUT_W1 466944

__device__ __forceinline__ bf16 f2b(float f){
  unsigned int i = __builtin_bit_cast(unsigned int, f);
  unsigned int r = i + 0x7fffu + ((i >> 16) & 1u);
  unsigned short h = (unsigned short)(r >> 16);
  return __builtin_bit_cast(bf16, h);
}
__device__ __forceinline__ float b2f(bf16 x){
  unsigned short u = __builtin_bit_cast(unsigned short, x);
  union { unsigned int i; float f; } v; v.i = ((unsigned int)u) << 16; return v.f;
}
__device__ __forceinline__ bf16x8 ld8f(const float* p, float sc){
  f32x4 a = *(const f32x4*)p;
  f32x4 b = *(const f32x4*)(p + 4);
  bf16x8 r;
  #pragma unroll
  for (int j = 0; j < 4; ++j){ r[j] = f2b(a[j]*sc); r[4+j] = f2b(b[j]*sc); }
  return r;
}

// ---------------- prep: fp32 weights -> bf16 in ws, BN scale folded ----------------
__global__ __launch_bounds__(256)
void prep_kernel(const float* s0, const float* s1, const float* s2, const float* s3,
                 const float* s4, const float* s5, const float* s6, const float* s7,
                 const float* g0, const float* g1, const float* g3, const float* g4,
                 bf16* dst)
{
  const int offs[8] = {WS_PRE_W0, WS_PRE_W1, WS_PRE_W2, WS_MLP_W0,
                       WS_MLP_W1, WS_MLP_W2, WS_OUT_W0, WS_OUT_W1};
  const int sz[8]   = {8192, 65536, 65536, 131072, 65536, 65536, 65536, 65536};
  const int ld[8]   = {32, 256, 256, 512, 256, 256, 256, 256};
  int r = blockIdx.y;
  const float* src = s0;
  if (r == 1) src = s1; else if (r == 2) src = s2; else if (r == 3) src = s3;
  else if (r == 4) src = s4; else if (r == 5) src = s5; else if (r == 6) src = s6;
  else if (r == 7) src = s7;
  const float* gp = (r==0)?g0:(r==1)?g1:(r==3)?g3:(r==4)?g4:nullptr;
  int i = (blockIdx.x*256 + threadIdx.x)*8;
  if (i < sz[r]){
    float sc = gp ? gp[i/ld[r]]*BNI : 1.0f;   // i..i+7 same row (ld % 8 == 0)
    *(bf16x8*)&dst[offs[r] + i] = ld8f(src + i, sc);
  }
}

// ---- stage one half-K chunk (32 feats x 128 k = 8 KB) via global_load_lds:
// LDS dest is LINEAR (wave base + lane*16 = HW semantics); swizzle applied by
// inverse-XOR on the GLOBAL source column (m173 pattern). Read side XOR unchanged.
// chunk c: nt = c>>1 (feature tile), kh = c&1 (K half)
__device__ __forceinline__ void stageAsyncK(const bf16* W, int ldK, int c, bf16* buf, int tid){
  int nt = c >> 1, kh = c & 1;
  int wv = tid >> 6, lane = tid & 63;
  #pragma unroll
  for (int i = 0; i < 2; ++i){
    int id = wv*64 + lane + 256*i;      // linear 16B-slot index == dest/16
    int fr = id >> 4, kcd = id & 15;    // dest slot (fr, kcd)
    int kcs = kcd ^ (fr & 15);          // source column (XOR involution)
    const bf16* g = W + (size_t)(nt*32 + fr)*ldK + kh*128 + kcs*8;
    bf16* l = buf + (size_t)(wv*64 + 256*i)*8;   // wave-uniform base; HW adds lane*16
    __builtin_amdgcn_global_load_lds(
        (const __attribute__((address_space(1))) void*)g,
        (__attribute__((address_space(3))) void*)l,
        16, 0, 0);
  }
}

// transposed epilogue: lane owns act-row `row`; 4 consecutive features per quad
template<int RELU, int MASK, int ADDT2>
__device__ __forceinline__ void epiT(
    const f32x16& acc, int nt, int row, int poly, float mk, bool valid,
    bf16* sAct, const bf16* sT2, const float* bptr, int hi)
{
  #pragma unroll
  for (int q2 = 0; q2 < 4; ++q2){
    int f0 = nt*32 + 8*q2 + 4*hi;
    f32x4 bb = *(const f32x4*)(bptr + f0);
    bf16x4 tv = {};
    if (ADDT2) tv = *(const bf16x4*)&sT2[poly*256 + f0];
    bf16x4 o;
    #pragma unroll
    for (int j = 0; j < 4; ++j){
      float v = acc[4*q2 + j];
      if (ADDT2) v += b2f(tv[j]);
      v += bb[j];
      if (RELU) v = fmaxf(v, 0.0f);
      if (MASK) v *= mk;
      o[j] = f2b(v);
    }
    if (valid)
      *(bf16x4*)&sAct[row*256 + (((nt*4 + q2) ^ (row & 31))<<3) + 4*hi] = o;
  }
}

// 256->256 layer: async-staged dbuf 8KB weight chunks (1 barrier/chunk), transposed MFMA
// 16 chunks = 8 feature tiles x 2 K-halves; acc carried across each K-half pair.
// global_load_lds drains at the end-of-chunk barrier (implicit vmcnt(0) before s_barrier).
template<int RELU, int MASK, int ADDT2>
__device__ __forceinline__ void layerT(
    bf16* sAct, bf16* wb0, bf16* wb1, const bf16* sT2,
    const bf16* W, int ldK, const float* bptr,
    const int* maskp, int blk, int row, int rowc, int lane32, int hi, int tid)
{
  bf16x8 B[16];
  #pragma unroll
  for (int t = 0; t < 16; ++t)
    B[t] = *(const bf16x8*)&sAct[AADDR(rowc, 2*t + hi)];   // own-row, intra-wave dep

  float mk = 1.0f;
  if (MASK){
    int g = blk*NROW + row;
    mk = (row < NROW && g < TOTROW && maskp[g]) ? 1.0f : 0.0f;
  }
  const int poly = rowc/20;
  const bool valid = row < NROW;

  stageAsyncK(W, ldK, 0, wb0, tid);      // chunk 0 -> wb0 (wb free: prior readers barriered)
  __syncthreads();                       // drains vmcnt; chunk 0 visible
  f32x16 acc;
  #pragma unroll 1
  for (int c = 0; c < 16; ++c){
    const bf16* cur = (c & 1) ? wb1 : wb0;
    bf16* nxt = (c & 1) ? wb0 : wb1;
    if (c < 15) stageAsyncK(W, ldK, c + 1, nxt, tid);  // async DMA under compute
    const int kh = c & 1;
    bf16x8 wf[8];
    const bf16* base = cur + lane32*128;
    #pragma unroll
    for (int t = 0; t < 8; ++t)
      wf[t] = *(const bf16x8*)(base + (((2*t + hi) ^ (lane32 & 15))<<3));
    if (kh == 0){
      #pragma unroll
      for (int j = 0; j < 16; ++j) acc[j] = 0.0f;
    }
    #pragma unroll
    for (int t = 0; t < 8; ++t)
      acc = __builtin_amdgcn_mfma_f32_32x32x16_bf16(wf[t], B[8*kh + t], acc, 0, 0, 0);
    if (kh == 1)
      epiT<RELU,MASK,ADDT2>(acc, c >> 1, row, poly, mk, valid, sAct, sT2, bptr, hi);
    __syncthreads();                     // chunk c+1 staged AND compute c done
  }
}

// pool 20 mask-zeroed rows per polyline -> sPool rows 0..5 (swizzled)
__device__ __forceinline__ void poolT(const bf16* sAct, bf16* sPool, int tid){
  if (tid < 192){
    int poly = tid >> 5, c = tid & 31;
    float m[8];
    bf16x8 v0 = *(const bf16x8*)&sAct[AADDR(poly*20, c)];
    #pragma unroll
    for (int j = 0; j < 8; ++j) m[j] = b2f(v0[j]);
    for (int r = 1; r < 20; ++r){
      bf16x8 v = *(const bf16x8*)&sAct[AADDR(poly*20 + r, c)];
      #pragma unroll
      for (int j = 0; j < 8; ++j) m[j] = fmaxf(m[j], b2f(v[j]));
    }
    bf16x8 o;
    #pragma unroll
    for (int j = 0; j < 8; ++j) o[j] = f2b(m[j]);
    *(bf16x8*)&sPool[AADDR(poly, c)] = o;
  }
}

__global__ __launch_bounds__(256) __attribute__((amdgpu_waves_per_eu(2, 2)))
void traj_kernel(const float* __restrict__ poly, const int* __restrict__ maskp,
                 const float* pre_b0, const float* pre_b1, const float* pre_bias2,
                 const float* mlp_b0, const float* mlp_b1, const float* mlp_bias2,
                 const float* out_b0, const float* out_b1,
                 const bf16* __restrict__ ws,
                 float* __restrict__ outp)
{
  extern __shared__ char smem[];
  bf16*  sAct   = (bf16*)(smem + OFF_ACT);
  bf16*  wb0    = (bf16*)(smem + OFF_WB0);
  bf16*  wb1    = (bf16*)(smem + OFF_WB1);
  bf16*  sT2    = (bf16*)(smem + OFF_T2);
  float* sValid = (float*)(smem + OFF_VAL);
  bf16*  sPool  = wb0;                       // pooled tile aliases wb0 (barrier-separated)
  bf16*  sY     = sAct;                      // y tile aliases sAct (dead after pool2)

  const int tid = threadIdx.x;
  const int w = tid >> 6, L = tid & 63, lane32 = L & 31, hi = L >> 5;
  const int row  = w*32 + lane32;            // 0..127; valid < 120
  const int rowc = row < NROW ? row : NROW - 1;
  const int blk = blockIdx.x;

  const bf16* pw0 = ws + WS_PRE_W0;
  const bf16* pw1 = ws + WS_PRE_W1;
  const bf16* pw2 = ws + WS_PRE_W2;
  const bf16* mw0 = ws + WS_MLP_W0;
  const bf16* mw1 = ws + WS_MLP_W1;
  const bf16* mw2 = ws + WS_MLP_W2;
  const bf16* ow0 = ws + WS_OUT_W0;
  const bf16* ow1 = ws + WS_OUT_W1;

  // ---- phase 0: input (120x32 fp32 -> bf16, swizzled; OOB rows zero) ----
  #pragma unroll
  for (int i = 0; i < 2; ++i){
    int id = tid + 256*i;
    if (id < 480){
      int r = id >> 2, c = id & 3;
      int grow = blk*NROW + r;
      bf16x8 v = {};
      if (grow < TOTROW) v = ld8f(poly + (size_t)grow*32 + c*8, 1.0f);
      *(bf16x8*)&sAct[AADDR(r, c)] = v;
    }
  }
  __syncthreads();
  if (tid < NPOLYB){
    float v = 0.0f;
    #pragma unroll
    for (int r = 0; r < 20; ++r){
      int g = blk*NROW + tid*20 + r;
      if (g < TOTROW && maskp[g]) v = 1.0f;
    }
    sValid[tid] = v;                         // consumed in out1 (after several barriers)
  }

  // ---- pre0: K=32, transposed, W direct from ws (tiny) ----
  {
    bf16x8 B0 = *(const bf16x8*)&sAct[AADDR(rowc, hi)];
    bf16x8 B1 = *(const bf16x8*)&sAct[AADDR(rowc, 2 + hi)];
    #pragma unroll 1
    for (int nt = 0; nt < 8; ++nt){
      const bf16* p = pw0 + (size_t)(nt*32 + lane32)*32 + 8*hi;
      bf16x8 w0 = *(const bf16x8*)p;
      bf16x8 w1 = *(const bf16x8*)(p + 16);
      f32x16 acc = {};
      acc = __builtin_amdgcn_mfma_f32_32x32x16_bf16(w0, B0, acc, 0, 0, 0);
      acc = __builtin_amdgcn_mfma_f32_32x32x16_bf16(w1, B1, acc, 0, 0, 0);
      epiT<1,0,0>(acc, nt, row, 0, 1.0f, row < NROW, sAct, sT2, pre_b0, hi);
    }
  }
  __syncthreads();      // pre0 done; wb buffers free for pre1 staging

  // ---- pre1, pre2 (async dbuf) ----
  layerT<1,0,0>(sAct, wb0, wb1, sT2, pw1, 256, pre_b1,    maskp, blk, row, rowc, lane32, hi, tid);
  layerT<0,1,0>(sAct, wb0, wb1, sT2, pw2, 256, pre_bias2, maskp, blk, row, rowc, lane32, hi, tid);

  // last layer barrier done: all pre2 writes visible
  poolT(sAct, sPool, tid);
  __syncthreads();                    // pool1 visible

  // ---- t2 = pooled @ mlp_w0'[:,256:]^T : wave w handles nt = w, w+4 (direct global) ----
  {
    bf16x8 Bp[16];
    #pragma unroll
    for (int t = 0; t < 16; ++t)
      Bp[t] = *(const bf16x8*)&sPool[AADDR((lane32 < NPOLYB ? lane32 : 0), 2*t + hi)];
    #pragma unroll 1
    for (int it = 0; it < 2; ++it){
      int nt = w + 4*it;
      const bf16* p = mw0 + (size_t)(nt*32 + lane32)*512 + 256 + 8*hi;
      f32x16 acc = {};
      #pragma unroll
      for (int t = 0; t < 16; ++t){
        bf16x8 wf = *(const bf16x8*)(p + 16*t);
        acc = __builtin_amdgcn_mfma_f32_32x32x16_bf16(wf, Bp[t], acc, 0, 0, 0);
      }
      if (lane32 < NPOLYB){
        #pragma unroll
        for (int q2 = 0; q2 < 4; ++q2){
          int f0 = nt*32 + 8*q2 + 4*hi;
          bf16x4 o;
          #pragma unroll
          for (int j = 0; j < 4; ++j) o[j] = f2b(acc[4*q2 + j]);
          *(bf16x4*)&sT2[lane32*256 + f0] = o;
        }
      }
    }
  }
  __syncthreads();                    // sT2 ready; sPool(wb0) reads done

  // ---- mlp0 (x-half + t2), mlp1, mlp2 (async dbuf) ----
  layerT<1,0,1>(sAct, wb0, wb1, sT2, mw0, 512, mlp_b0,    maskp, blk, row, rowc, lane32, hi, tid);
  layerT<1,0,0>(sAct, wb0, wb1, sT2, mw1, 256, mlp_b1,    maskp, blk, row, rowc, lane32, hi, tid);
  layerT<0,1,0>(sAct, wb0, wb1, sT2, mw2, 256, mlp_bias2, maskp, blk, row, rowc, lane32, hi, tid);

  // last layer barrier done
  poolT(sAct, sPool, tid);
  __syncthreads();                    // pool2 visible; sAct dead -> sY

  // ---- out0: y = relu(pool2 @ ow0^T + b0) -> sY rows 0..5; wave w: nt = w, w+4 ----
  {
    bf16x8 Bp[16];
    #pragma unroll
    for (int t = 0; t < 16; ++t)
      Bp[t] = *(const bf16x8*)&sPool[AADDR((lane32 < NPOLYB ? lane32 : 0), 2*t + hi)];
    #pragma unroll 1
    for (int it = 0; it < 2; ++it){
      int nt = w + 4*it;
      const bf16* p = ow0 + (size_t)(nt*32 + lane32)*256 + 8*hi;
      f32x16 acc = {};
      #pragma unroll
      for (int t = 0; t < 16; ++t){
        bf16x8 wf = *(const bf16x8*)(p + 16*t);
        acc = __builtin_amdgcn_mfma_f32_32x32x16_bf16(wf, Bp[t], acc, 0, 0, 0);
      }
      if (lane32 < NPOLYB){
        #pragma unroll
        for (int q2 = 0; q2 < 4; ++q2){
          int f0 = nt*32 + 8*q2 + 4*hi;
          f32x4 bb = *(const f32x4*)(out_b0 + f0);
          bf16x4 o;
          #pragma unroll
          for (int j = 0; j < 4; ++j) o[j] = f2b(fmaxf(acc[4*q2 + j] + bb[j], 0.0f));
          *(bf16x4*)&sY[lane32*256 + (((nt*4 + q2) ^ (lane32 & 31))<<3) + 4*hi] = o;
        }
      }
    }
  }
  __syncthreads();                    // y visible

  // ---- out1: z = (y @ ow1^T + b1) * valid -> global fp32; wave w: nt = w, w+4 ----
  {
    bf16x8 By[16];
    #pragma unroll
    for (int t = 0; t < 16; ++t)
      By[t] = *(const bf16x8*)&sY[AADDR((lane32 < NPOLYB ? lane32 : 0), 2*t + hi)];
    int gp = blk*NPOLYB + lane32;
    float vd = (lane32 < NPOLYB) ? sValid[lane32] : 0.0f;
    #pragma unroll 1
    for (int it = 0; it < 2; ++it){
      int nt = w + 4*it;
      const bf16* p = ow1 + (size_t)(nt*32 + lane32)*256 + 8*hi;
      f32x16 acc = {};
      #pragma unroll
      for (int t = 0; t < 16; ++t){
        bf16x8 wf = *(const bf16x8*)(p + 16*t);
        acc = __builtin_amdgcn_mfma_f32_32x32x16_bf16(wf, By[t], acc, 0, 0, 0);
      }
      if (lane32 < NPOLYB && gp < NPOLY){
        #pragma unroll
        for (int q2 = 0; q2 < 4; ++q2){
          int f0 = nt*32 + 8*q2 + 4*hi;
          f32x4 bb = *(const f32x4*)(out_b1 + f0);
          f32x4 o;
          #pragma unroll
          for (int j = 0; j < 4; ++j) o[j] = (acc[4*q2 + j] + bb[j]) * vd;
          *(f32x4*)&outp[(size_t)gp*256 + f0] = o;
        }
      }
    }
  }
}

extern "C" void kernel_launch(void* const* d_in, const int* in_sizes, int n_in,
                              void* d_out, int out_size, void* d_ws, size_t ws_size,
                              hipStream_t stream)
{
  const float* poly      = (const float*)d_in[0];
  const int*   maskp     = (const int*)  d_in[1];
  const float* pre_w0    = (const float*)d_in[2];
  const float* pre_g0    = (const float*)d_in[3];
  const float* pre_b0    = (const float*)d_in[4];
  const float* pre_w1    = (const float*)d_in[5];
  const float* pre_g1    = (const float*)d_in[6];
  const float* pre_b1    = (const float*)d_in[7];
  const float* pre_w2    = (const float*)d_in[8];
  const float* pre_bias2 = (const float*)d_in[9];
  const float* mlp_w0    = (const float*)d_in[10];
  const float* mlp_g0    = (const float*)d_in[11];
  const float* mlp_b0    = (const float*)d_in[12];
  const float* mlp_w1    = (const float*)d_in[13];
  const float* mlp_g1    = (const float*)d_in[14];
  const float* mlp_b1    = (const float*)d_in[15];
  const float* mlp_w2    = (const float*)d_in[16];
  const float* mlp_bias2 = (const float*)d_in[17];
  const float* out_w0    = (const float*)d_in[18];
  const float* out_b0    = (const float*)d_in[19];
  const float* out_w1    = (const float*)d_in[20];
  const float* out_b1    = (const float*)d_in[21];

  bf16* ws = (bf16*)d_ws;   // 1,064,960 B of ws used

  (void)hipFuncSetAttribute((const void*)&traj_kernel,
                            hipFuncAttributeMaxDynamicSharedMemorySize, LDS_TOTAL);

  prep_kernel<<<dim3(64, 8), dim3(256), 0, stream>>>(
      pre_w0, pre_w1, pre_w2, mlp_w0, mlp_w1, mlp_w2, out_w0, out_w1,
      pre_g0, pre_g1, mlp_g0, mlp_g1, ws);

  traj_kernel<<<dim3(NBLK), dim3(256), LDS_TOTAL, stream>>>(
      poly, maskp,
      pre_b0, pre_b1, pre_bias2,
      mlp_b0, mlp_b1, mlp_bias2,
      out_b0, out_b1,
      ws, (float*)d_out);
}

// Round 9
// 338.362 us; speedup vs baseline: 2.3467x; 2.3343x over previous
//
#include <hip/hip_runtime.h>
#include <stdint.h>
#include <stddef.h>

typedef __bf16 bf16;
typedef __bf16 bf16x4 __attribute__((ext_vector_type(4)));
typedef __bf16 bf16x8 __attribute__((ext_vector_type(8)));
typedef float f32x4 __attribute__((ext_vector_type(4)));
typedef float f32x16 __attribute__((ext_vector_type(16)));

#define BNI 0.9999950000374996f  // 1/sqrt(1+1e-5)
#define NROW 120                  // valid rows per block (6 polylines x 20)
#define NPOLYB 6
#define TOTROW 163840
#define NPOLY 8192
#define NBLK 1366                 // ceil(163840/120)

// swizzled act addressing: row-major stride 256 bf16, 16B chunks XOR-swizzled by row
#define AADDR(r, ch) ((r)*256 + ((((ch) ^ ((r)&31)))<<3))

// dynamic LDS layout (bytes) — 80920 B/block => 2 blocks/CU
#define OFF_ACT  0                // 120*512 = 61440 (sAct; rows 0..5 reused as sY)
#define OFF_WB0  61440            // 8192: weight chunk buf0 (aliased by sPool)
#define OFF_WB1  69632            // 8192: weight chunk buf1
#define OFF_T2   77824            // 6*256*2 = 3072 (t2, bf16)
#define OFF_VAL  80896            // 6*4 = 24
#define LDS_TOTAL 80920

// ws layout (bf16 elems) — BN-folded weights
#define WS_PRE_W0 0
#define WS_PRE_W1 8192
#define WS_PRE_W2 73728
#define WS_MLP_W0 139264
#define WS_MLP_W1 270336
#define WS_MLP_W2 335872
#define WS_OUT_W0 401408
#define WS_OUT_W1 466944

__device__ __forceinline__ bf16 f2b(float f){
  unsigned int i = __builtin_bit_cast(unsigned int, f);
  unsigned int r = i + 0x7fffu + ((i >> 16) & 1u);
  unsigned short h = (unsigned short)(r >> 16);
  return __builtin_bit_cast(bf16, h);
}
__device__ __forceinline__ float b2f(bf16 x){
  unsigned short u = __builtin_bit_cast(unsigned short, x);
  union { unsigned int i; float f; } v; v.i = ((unsigned int)u) << 16; return v.f;
}
__device__ __forceinline__ bf16x8 ld8f(const float* p, float sc){
  f32x4 a = *(const f32x4*)p;
  f32x4 b = *(const f32x4*)(p + 4);
  bf16x8 r;
  #pragma unroll
  for (int j = 0; j < 4; ++j){ r[j] = f2b(a[j]*sc); r[4+j] = f2b(b[j]*sc); }
  return r;
}

// ---------------- prep: fp32 weights -> bf16 in ws, BN scale folded ----------------
__global__ __launch_bounds__(256)
void prep_kernel(const float* s0, const float* s1, const float* s2, const float* s3,
                 const float* s4, const float* s5, const float* s6, const float* s7,
                 const float* g0, const float* g1, const float* g3, const float* g4,
                 bf16* dst)
{
  const int offs[8] = {WS_PRE_W0, WS_PRE_W1, WS_PRE_W2, WS_MLP_W0,
                       WS_MLP_W1, WS_MLP_W2, WS_OUT_W0, WS_OUT_W1};
  const int sz[8]   = {8192, 65536, 65536, 131072, 65536, 65536, 65536, 65536};
  const int ld[8]   = {32, 256, 256, 512, 256, 256, 256, 256};
  int r = blockIdx.y;
  const float* src = s0;
  if (r == 1) src = s1; else if (r == 2) src = s2; else if (r == 3) src = s3;
  else if (r == 4) src = s4; else if (r == 5) src = s5; else if (r == 6) src = s6;
  else if (r == 7) src = s7;
  const float* gp = (r==0)?g0:(r==1)?g1:(r==3)?g3:(r==4)?g4:nullptr;
  int i = (blockIdx.x*256 + threadIdx.x)*8;
  if (i < sz[r]){
    float sc = gp ? gp[i/ld[r]]*BNI : 1.0f;   // i..i+7 same row (ld % 8 == 0)
    *(bf16x8*)&dst[offs[r] + i] = ld8f(src + i, sc);
  }
}

// ---- stage one half-K chunk (32 feats x 128 k = 8 KB) via global_load_lds:
// LDS dest LINEAR (wave base + lane*16); swizzle applied via inverse-XOR on the
// GLOBAL source column (involution). Read side XOR unchanged.
// chunk c: nt = c>>1 (feature tile), kh = c&1 (K half)
__device__ __forceinline__ void stageAsyncK(const bf16* W, int ldK, int c, bf16* buf, int tid){
  int nt = c >> 1, kh = c & 1;
  int wv = tid >> 6, lane = tid & 63;
  #pragma unroll
  for (int i = 0; i < 2; ++i){
    int id = wv*64 + lane + 256*i;      // linear 16B-slot index == dest/16
    int fr = id >> 4, kcd = id & 15;    // dest slot (fr, kcd)
    int kcs = kcd ^ (fr & 15);          // source column (XOR involution)
    const bf16* g = W + (size_t)(nt*32 + fr)*ldK + kh*128 + kcs*8;
    bf16* l = buf + (size_t)(wv*64 + 256*i)*8;   // wave-uniform base; HW adds lane*16
    __builtin_amdgcn_global_load_lds(
        (const __attribute__((address_space(1))) void*)g,
        (__attribute__((address_space(3))) void*)l,
        16, 0, 0);
  }
}

// transposed epilogue: lane owns act-row `row`; 4 consecutive features per quad
template<int RELU, int MASK, int ADDT2>
__device__ __forceinline__ void epiT(
    const f32x16& acc, int nt, int row, int poly, float mk, bool valid,
    bf16* sAct, const bf16* sT2, const float* bptr, int hi)
{
  #pragma unroll
  for (int q2 = 0; q2 < 4; ++q2){
    int f0 = nt*32 + 8*q2 + 4*hi;
    f32x4 bb = *(const f32x4*)(bptr + f0);
    bf16x4 tv = {};
    if (ADDT2) tv = *(const bf16x4*)&sT2[poly*256 + f0];
    bf16x4 o;
    #pragma unroll
    for (int j = 0; j < 4; ++j){
      float v = acc[4*q2 + j];
      if (ADDT2) v += b2f(tv[j]);
      v += bb[j];
      if (RELU) v = fmaxf(v, 0.0f);
      if (MASK) v *= mk;
      o[j] = f2b(v);
    }
    if (valid)
      *(bf16x4*)&sAct[row*256 + (((nt*4 + q2) ^ (row & 31))<<3) + 4*hi] = o;
  }
}

// 256->256 layer: async dbuf 8KB weight chunks; K-half PAIRS manually unrolled so
// every B[] index is COMPILE-TIME constant (rule #20: runtime-indexed ext_vector
// arrays go to scratch — this was the 438MB WRITE_SIZE spill).
template<int RELU, int MASK, int ADDT2>
__device__ __forceinline__ void layerT(
    bf16* sAct, bf16* wb0, bf16* wb1, const bf16* sT2,
    const bf16* W, int ldK, const float* bptr,
    const int* maskp, int blk, int row, int rowc, int lane32, int hi, int tid)
{
  bf16x8 B[16];
  #pragma unroll
  for (int t = 0; t < 16; ++t)
    B[t] = *(const bf16x8*)&sAct[AADDR(rowc, 2*t + hi)];   // own-row, intra-wave dep

  float mk = 1.0f;
  if (MASK){
    int g = blk*NROW + row;
    mk = (row < NROW && g < TOTROW && maskp[g]) ? 1.0f : 0.0f;
  }
  const int poly = rowc/20;
  const bool valid = row < NROW;

  stageAsyncK(W, ldK, 0, wb0, tid);      // chunk 0 -> wb0 (prior readers barriered)
  __syncthreads();                       // drains vmcnt; chunk 0 visible
  #pragma unroll 1
  for (int p = 0; p < 8; ++p){
    f32x16 acc;
    // ---- chunk 2p (kh=0): compute wb0, stage 2p+1 -> wb1 ----
    stageAsyncK(W, ldK, 2*p + 1, wb1, tid);   // async DMA under compute
    {
      bf16x8 wf[8];
      const bf16* base = wb0 + lane32*128;
      #pragma unroll
      for (int t = 0; t < 8; ++t)
        wf[t] = *(const bf16x8*)(base + (((2*t + hi) ^ (lane32 & 15))<<3));
      #pragma unroll
      for (int j = 0; j < 16; ++j) acc[j] = 0.0f;
      #pragma unroll
      for (int t = 0; t < 8; ++t)
        acc = __builtin_amdgcn_mfma_f32_32x32x16_bf16(wf[t], B[t], acc, 0, 0, 0);
    }
    __syncthreads();                     // 2p+1 staged AND wb0 reads done
    // ---- chunk 2p+1 (kh=1): compute wb1, stage 2p+2 -> wb0 ----
    if (p < 7) stageAsyncK(W, ldK, 2*p + 2, wb0, tid);
    {
      bf16x8 wf[8];
      const bf16* base = wb1 + lane32*128;
      #pragma unroll
      for (int t = 0; t < 8; ++t)
        wf[t] = *(const bf16x8*)(base + (((2*t + hi) ^ (lane32 & 15))<<3));
      #pragma unroll
      for (int t = 0; t < 8; ++t)
        acc = __builtin_amdgcn_mfma_f32_32x32x16_bf16(wf[t], B[8 + t], acc, 0, 0, 0);
      epiT<RELU,MASK,ADDT2>(acc, p, row, poly, mk, valid, sAct, sT2, bptr, hi);
    }
    __syncthreads();                     // 2p+2 staged AND wb1 reads done
  }
}

// pool 20 mask-zeroed rows per polyline -> sPool rows 0..5 (swizzled)
__device__ __forceinline__ void poolT(const bf16* sAct, bf16* sPool, int tid){
  if (tid < 192){
    int poly = tid >> 5, c = tid & 31;
    float m[8];
    bf16x8 v0 = *(const bf16x8*)&sAct[AADDR(poly*20, c)];
    #pragma unroll
    for (int j = 0; j < 8; ++j) m[j] = b2f(v0[j]);
    for (int r = 1; r < 20; ++r){
      bf16x8 v = *(const bf16x8*)&sAct[AADDR(poly*20 + r, c)];
      #pragma unroll
      for (int j = 0; j < 8; ++j) m[j] = fmaxf(m[j], b2f(v[j]));
    }
    bf16x8 o;
    #pragma unroll
    for (int j = 0; j < 8; ++j) o[j] = f2b(m[j]);
    *(bf16x8*)&sPool[AADDR(poly, c)] = o;
  }
}

__global__ __launch_bounds__(256) __attribute__((amdgpu_waves_per_eu(2, 2)))
void traj_kernel(const float* __restrict__ poly, const int* __restrict__ maskp,
                 const float* pre_b0, const float* pre_b1, const float* pre_bias2,
                 const float* mlp_b0, const float* mlp_b1, const float* mlp_bias2,
                 const float* out_b0, const float* out_b1,
                 const bf16* __restrict__ ws,
                 float* __restrict__ outp)
{
  extern __shared__ char smem[];
  bf16*  sAct   = (bf16*)(smem + OFF_ACT);
  bf16*  wb0    = (bf16*)(smem + OFF_WB0);
  bf16*  wb1    = (bf16*)(smem + OFF_WB1);
  bf16*  sT2    = (bf16*)(smem + OFF_T2);
  float* sValid = (float*)(smem + OFF_VAL);
  bf16*  sPool  = wb0;                       // pooled tile aliases wb0 (barrier-separated)
  bf16*  sY     = sAct;                      // y tile aliases sAct (dead after pool2)

  const int tid = threadIdx.x;
  const int w = tid >> 6, L = tid & 63, lane32 = L & 31, hi = L >> 5;
  const int row  = w*32 + lane32;            // 0..127; valid < 120
  const int rowc = row < NROW ? row : NROW - 1;
  const int blk = blockIdx.x;

  const bf16* pw0 = ws + WS_PRE_W0;
  const bf16* pw1 = ws + WS_PRE_W1;
  const bf16* pw2 = ws + WS_PRE_W2;
  const bf16* mw0 = ws + WS_MLP_W0;
  const bf16* mw1 = ws + WS_MLP_W1;
  const bf16* mw2 = ws + WS_MLP_W2;
  const bf16* ow0 = ws + WS_OUT_W0;
  const bf16* ow1 = ws + WS_OUT_W1;

  // ---- phase 0: input (120x32 fp32 -> bf16, swizzled; OOB rows zero) ----
  #pragma unroll
  for (int i = 0; i < 2; ++i){
    int id = tid + 256*i;
    if (id < 480){
      int r = id >> 2, c = id & 3;
      int grow = blk*NROW + r;
      bf16x8 v = {};
      if (grow < TOTROW) v = ld8f(poly + (size_t)grow*32 + c*8, 1.0f);
      *(bf16x8*)&sAct[AADDR(r, c)] = v;
    }
  }
  __syncthreads();
  if (tid < NPOLYB){
    float v = 0.0f;
    #pragma unroll
    for (int r = 0; r < 20; ++r){
      int g = blk*NROW + tid*20 + r;
      if (g < TOTROW && maskp[g]) v = 1.0f;
    }
    sValid[tid] = v;                         // consumed in out1 (after several barriers)
  }

  // ---- pre0: K=32, transposed, W direct from ws (tiny) ----
  {
    bf16x8 B0 = *(const bf16x8*)&sAct[AADDR(rowc, hi)];
    bf16x8 B1 = *(const bf16x8*)&sAct[AADDR(rowc, 2 + hi)];
    #pragma unroll 1
    for (int nt = 0; nt < 8; ++nt){
      const bf16* p = pw0 + (size_t)(nt*32 + lane32)*32 + 8*hi;
      bf16x8 w0 = *(const bf16x8*)p;
      bf16x8 w1 = *(const bf16x8*)(p + 16);
      f32x16 acc = {};
      acc = __builtin_amdgcn_mfma_f32_32x32x16_bf16(w0, B0, acc, 0, 0, 0);
      acc = __builtin_amdgcn_mfma_f32_32x32x16_bf16(w1, B1, acc, 0, 0, 0);
      epiT<1,0,0>(acc, nt, row, 0, 1.0f, row < NROW, sAct, sT2, pre_b0, hi);
    }
  }
  __syncthreads();      // pre0 done; wb buffers free for pre1 staging

  // ---- pre1, pre2 (async dbuf) ----
  layerT<1,0,0>(sAct, wb0, wb1, sT2, pw1, 256, pre_b1,    maskp, blk, row, rowc, lane32, hi, tid);
  layerT<0,1,0>(sAct, wb0, wb1, sT2, pw2, 256, pre_bias2, maskp, blk, row, rowc, lane32, hi, tid);

  // last layer barrier done: all pre2 writes visible
  poolT(sAct, sPool, tid);
  __syncthreads();                    // pool1 visible

  // ---- t2 = pooled @ mlp_w0'[:,256:]^T : wave w handles nt = w, w+4 (direct global) ----
  {
    bf16x8 Bp[16];
    #pragma unroll
    for (int t = 0; t < 16; ++t)
      Bp[t] = *(const bf16x8*)&sPool[AADDR((lane32 < NPOLYB ? lane32 : 0), 2*t + hi)];
    #pragma unroll 1
    for (int it = 0; it < 2; ++it){
      int nt = w + 4*it;
      const bf16* p = mw0 + (size_t)(nt*32 + lane32)*512 + 256 + 8*hi;
      f32x16 acc = {};
      #pragma unroll
      for (int t = 0; t < 16; ++t){
        bf16x8 wf = *(const bf16x8*)(p + 16*t);
        acc = __builtin_amdgcn_mfma_f32_32x32x16_bf16(wf, Bp[t], acc, 0, 0, 0);
      }
      if (lane32 < NPOLYB){
        #pragma unroll
        for (int q2 = 0; q2 < 4; ++q2){
          int f0 = nt*32 + 8*q2 + 4*hi;
          bf16x4 o;
          #pragma unroll
          for (int j = 0; j < 4; ++j) o[j] = f2b(acc[4*q2 + j]);
          *(bf16x4*)&sT2[lane32*256 + f0] = o;
        }
      }
    }
  }
  __syncthreads();                    // sT2 ready; sPool(wb0) reads done

  // ---- mlp0 (x-half + t2), mlp1, mlp2 (async dbuf) ----
  layerT<1,0,1>(sAct, wb0, wb1, sT2, mw0, 512, mlp_b0,    maskp, blk, row, rowc, lane32, hi, tid);
  layerT<1,0,0>(sAct, wb0, wb1, sT2, mw1, 256, mlp_b1,    maskp, blk, row, rowc, lane32, hi, tid);
  layerT<0,1,0>(sAct, wb0, wb1, sT2, mw2, 256, mlp_bias2, maskp, blk, row, rowc, lane32, hi, tid);

  // last layer barrier done
  poolT(sAct, sPool, tid);
  __syncthreads();                    // pool2 visible; sAct dead -> sY

  // ---- out0: y = relu(pool2 @ ow0^T + b0) -> sY rows 0..5; wave w: nt = w, w+4 ----
  {
    bf16x8 Bp[16];
    #pragma unroll
    for (int t = 0; t < 16; ++t)
      Bp[t] = *(const bf16x8*)&sPool[AADDR((lane32 < NPOLYB ? lane32 : 0), 2*t + hi)];
    #pragma unroll 1
    for (int it = 0; it < 2; ++it){
      int nt = w + 4*it;
      const bf16* p = ow0 + (size_t)(nt*32 + lane32)*256 + 8*hi;
      f32x16 acc = {};
      #pragma unroll
      for (int t = 0; t < 16; ++t){
        bf16x8 wf = *(const bf16x8*)(p + 16*t);
        acc = __builtin_amdgcn_mfma_f32_32x32x16_bf16(wf, Bp[t], acc, 0, 0, 0);
      }
      if (lane32 < NPOLYB){
        #pragma unroll
        for (int q2 = 0; q2 < 4; ++q2){
          int f0 = nt*32 + 8*q2 + 4*hi;
          f32x4 bb = *(const f32x4*)(out_b0 + f0);
          bf16x4 o;
          #pragma unroll
          for (int j = 0; j < 4; ++j) o[j] = f2b(fmaxf(acc[4*q2 + j] + bb[j], 0.0f));
          *(bf16x4*)&sY[lane32*256 + (((nt*4 + q2) ^ (lane32 & 31))<<3) + 4*hi] = o;
        }
      }
    }
  }
  __syncthreads();                    // y visible

  // ---- out1: z = (y @ ow1^T + b1) * valid -> global fp32; wave w: nt = w, w+4 ----
  {
    bf16x8 By[16];
    #pragma unroll
    for (int t = 0; t < 16; ++t)
      By[t] = *(const bf16x8*)&sY[AADDR((lane32 < NPOLYB ? lane32 : 0), 2*t + hi)];
    int gp = blk*NPOLYB + lane32;
    float vd = (lane32 < NPOLYB) ? sValid[lane32] : 0.0f;
    #pragma unroll 1
    for (int it = 0; it < 2; ++it){
      int nt = w + 4*it;
      const bf16* p = ow1 + (size_t)(nt*32 + lane32)*256 + 8*hi;
      f32x16 acc = {};
      #pragma unroll
      for (int t = 0; t < 16; ++t){
        bf16x8 wf = *(const bf16x8*)(p + 16*t);
        acc = __builtin_amdgcn_mfma_f32_32x32x16_bf16(wf, By[t], acc, 0, 0, 0);
      }
      if (lane32 < NPOLYB && gp < NPOLY){
        #pragma unroll
        for (int q2 = 0; q2 < 4; ++q2){
          int f0 = nt*32 + 8*q2 + 4*hi;
          f32x4 bb = *(const f32x4*)(out_b1 + f0);
          f32x4 o;
          #pragma unroll
          for (int j = 0; j < 4; ++j) o[j] = (acc[4*q2 + j] + bb[j]) * vd;
          *(f32x4*)&outp[(size_t)gp*256 + f0] = o;
        }
      }
    }
  }
}

extern "C" void kernel_launch(void* const* d_in, const int* in_sizes, int n_in,
                              void* d_out, int out_size, void* d_ws, size_t ws_size,
                              hipStream_t stream)
{
  const float* poly      = (const float*)d_in[0];
  const int*   maskp     = (const int*)  d_in[1];
  const float* pre_w0    = (const float*)d_in[2];
  const float* pre_g0    = (const float*)d_in[3];
  const float* pre_b0    = (const float*)d_in[4];
  const float* pre_w1    = (const float*)d_in[5];
  const float* pre_g1    = (const float*)d_in[6];
  const float* pre_b1    = (const float*)d_in[7];
  const float* pre_w2    = (const float*)d_in[8];
  const float* pre_bias2 = (const float*)d_in[9];
  const float* mlp_w0    = (const float*)d_in[10];
  const float* mlp_g0    = (const float*)d_in[11];
  const float* mlp_b0    = (const float*)d_in[12];
  const float* mlp_w1    = (const float*)d_in[13];
  const float* mlp_g1    = (const float*)d_in[14];
  const float* mlp_b1    = (const float*)d_in[15];
  const float* mlp_w2    = (const float*)d_in[16];
  const float* mlp_bias2 = (const float*)d_in[17];
  const float* out_w0    = (const float*)d_in[18];
  const float* out_b0    = (const float*)d_in[19];
  const float* out_w1    = (const float*)d_in[20];
  const float* out_b1    = (const float*)d_in[21];

  bf16* ws = (bf16*)d_ws;   // 1,064,960 B of ws used

  (void)hipFuncSetAttribute((const void*)&traj_kernel,
                            hipFuncAttributeMaxDynamicSharedMemorySize, LDS_TOTAL);

  prep_kernel<<<dim3(64, 8), dim3(256), 0, stream>>>(
      pre_w0, pre_w1, pre_w2, mlp_w0, mlp_w1, mlp_w2, out_w0, out_w1,
      pre_g0, pre_g1, mlp_g0, mlp_g1, ws);

  traj_kernel<<<dim3(NBLK), dim3(256), LDS_TOTAL, stream>>>(
      poly, maskp,
      pre_b0, pre_b1, pre_bias2,
      mlp_b0, mlp_b1, mlp_bias2,
      out_b0, out_b1,
      ws, (float*)d_out);
}

// Round 11
// 303.896 us; speedup vs baseline: 2.6129x; 1.1134x over previous
//
#include <hip/hip_runtime.h>
#include <stdint.h>
#include <stddef.h>

typedef __bf16 bf16;
typedef __bf16 bf16x4 __attribute__((ext_vector_type(4)));
typedef __bf16 bf16x8 __attribute__((ext_vector_type(8)));
typedef float f32x4 __attribute__((ext_vector_type(4)));
typedef float f32x16 __attribute__((ext_vector_type(16)));

#define BNI 0.9999950000374996f  // 1/sqrt(1+1e-5)
#define NROW 240                  // valid rows per block (12 polylines x 20)
#define NPOLYB 12
#define TOTROW 163840
#define NPOLY 8192
#define NBLK 683

// swizzled act addressing: row-major stride 256 bf16, 16B chunks XOR-swizzled by row
#define AADDR(r, ch) ((r)*256 + ((((ch) ^ ((r)&31)))<<3))

// dynamic LDS layout (bytes) — 161840 B/block => 1 block/CU
#define OFF_ACT  0                // 240*512 = 122880 (sAct; rows 0..11 reused as sY)
#define OFF_WB0  122880           // 16384: weight chunk buf0 (aliased by sPool)
#define OFF_WB1  139264           // 16384: weight chunk buf1
#define OFF_T2   155648           // 12*256*2 = 6144 (t2, bf16)
#define OFF_VAL  161792           // 12*4 = 48
#define LDS_TOTAL 161840

// ws layout (bf16 elems) — BN-folded weights
#define WS_PRE_W0 0
#define WS_PRE_W1 8192
#define WS_PRE_W2 73728
#define WS_MLP_W0 139264
#define WS_MLP_W1 270336
#define WS_MLP_W2 335872
#define WS_OUT_W0 401408
#define WS_OUT_W1 466944

__device__ __forceinline__ bf16 f2b(float f){
  unsigned int i = __builtin_bit_cast(unsigned int, f);
  unsigned int r = i + 0x7fffu + ((i >> 16) & 1u);
  unsigned short h = (unsigned short)(r >> 16);
  return __builtin_bit_cast(bf16, h);
}
__device__ __forceinline__ float b2f(bf16 x){
  unsigned short u = __builtin_bit_cast(unsigned short, x);
  union { unsigned int i; float f; } v; v.i = ((unsigned int)u) << 16; return v.f;
}
__device__ __forceinline__ bf16x8 ld8f(const float* p, float sc){
  f32x4 a = *(const f32x4*)p;
  f32x4 b = *(const f32x4*)(p + 4);
  bf16x8 r;
  #pragma unroll
  for (int j = 0; j < 4; ++j){ r[j] = f2b(a[j]*sc); r[4+j] = f2b(b[j]*sc); }
  return r;
}

// ---------------- prep: fp32 weights -> bf16 in ws, BN scale folded ----------------
__global__ __launch_bounds__(256)
void prep_kernel(const float* s0, const float* s1, const float* s2, const float* s3,
                 const float* s4, const float* s5, const float* s6, const float* s7,
                 const float* g0, const float* g1, const float* g3, const float* g4,
                 bf16* dst)
{
  const int offs[8] = {WS_PRE_W0, WS_PRE_W1, WS_PRE_W2, WS_MLP_W0,
                       WS_MLP_W1, WS_MLP_W2, WS_OUT_W0, WS_OUT_W1};
  const int sz[8]   = {8192, 65536, 65536, 131072, 65536, 65536, 65536, 65536};
  const int ld[8]   = {32, 256, 256, 512, 256, 256, 256, 256};
  int r = blockIdx.y;
  const float* src = s0;
  if (r == 1) src = s1; else if (r == 2) src = s2; else if (r == 3) src = s3;
  else if (r == 4) src = s4; else if (r == 5) src = s5; else if (r == 6) src = s6;
  else if (r == 7) src = s7;
  const float* gp = (r==0)?g0:(r==1)?g1:(r==3)?g3:(r==4)?g4:nullptr;
  int i = (blockIdx.x*256 + threadIdx.x)*8;
  if (i < sz[r]){
    float sc = gp ? gp[i/ld[r]]*BNI : 1.0f;   // i..i+7 same row (ld % 8 == 0)
    *(bf16x8*)&dst[offs[r] + i] = ld8f(src + i, sc);
  }
}

// ---- stage one 16KB chunk (32 feats x 256 k) via global_load_lds:
// LDS dest LINEAR (wave base + lane*16); swizzle via inverse-XOR on the GLOBAL
// source column (involution). Read-side XOR unchanged vs reg-staged version.
__device__ __forceinline__ void stageAsync32(const bf16* W, int ldK, int nt, bf16* buf, int tid){
  int wv = tid >> 6;
  #pragma unroll
  for (int i = 0; i < 2; ++i){
    int id = tid + 512*i;               // 1024 16B-slots; dest byte = id*16 (linear)
    int fr = id >> 5, kcd = id & 31;    // dest slot (feature row, col)
    int kcs = kcd ^ (fr & 31);          // source column (XOR involution)
    const bf16* g = W + (size_t)(nt*32 + fr)*ldK + kcs*8;
    bf16* l = buf + (size_t)(wv*64 + 512*i)*8;   // wave-uniform base; HW adds lane*16
    __builtin_amdgcn_global_load_lds(
        (const __attribute__((address_space(1))) void*)g,
        (__attribute__((address_space(3))) void*)l,
        16, 0, 0);
  }
}

// transposed epilogue: lane owns act-row `row`; 4 consecutive features per quad
template<int RELU, int MASK, int ADDT2>
__device__ __forceinline__ void epiT(
    const f32x16& acc, int nt, int row, int poly, float mk, bool valid,
    bf16* sAct, const bf16* sT2, const float* bptr, int hi)
{
  #pragma unroll
  for (int q2 = 0; q2 < 4; ++q2){
    int f0 = nt*32 + 8*q2 + 4*hi;
    f32x4 bb = *(const f32x4*)(bptr + f0);
    bf16x4 tv = {};
    if (ADDT2) tv = *(const bf16x4*)&sT2[poly*256 + f0];
    bf16x4 o;
    #pragma unroll
    for (int j = 0; j < 4; ++j){
      float v = acc[4*q2 + j];
      if (ADDT2) v += b2f(tv[j]);
      v += bb[j];
      if (RELU) v = fmaxf(v, 0.0f);
      if (MASK) v *= mk;
      o[j] = f2b(v);
    }
    if (valid)
      *(bf16x4*)&sAct[row*256 + (((nt*4 + q2) ^ (row & 31))<<3) + 4*hi] = o;
  }
}

// 256->256 layer: async dbuf 16KB weight chunks (1 barrier/chunk), transposed MFMA.
// All register arrays compile-time indexed (rule #20).
template<int RELU, int MASK, int ADDT2>
__device__ __forceinline__ void layerT(
    bf16* sAct, bf16* wb0, bf16* wb1, const bf16* sT2,
    const bf16* W, int ldK, const float* bptr,
    const int* maskp, int blk, int row, int rowc, int lane32, int hi, int tid)
{
  bf16x8 B[16];
  #pragma unroll
  for (int t = 0; t < 16; ++t)
    B[t] = *(const bf16x8*)&sAct[AADDR(rowc, 2*t + hi)];   // own-row, intra-wave dep

  float mk = 1.0f;
  if (MASK){
    int g = blk*NROW + row;
    mk = (row < NROW && g < TOTROW && maskp[g]) ? 1.0f : 0.0f;
  }
  const int poly = rowc/20;
  const bool valid = row < NROW;

  stageAsync32(W, ldK, 0, wb0, tid);     // chunk 0 -> wb0 (prior readers barriered)
  __syncthreads();                       // drains vmcnt; chunk 0 visible
  #pragma unroll 1
  for (int c = 0; c < 8; ++c){
    const bf16* cur = (c & 1) ? wb1 : wb0;
    bf16* nxt = (c & 1) ? wb0 : wb1;
    if (c < 7) stageAsync32(W, ldK, c + 1, nxt, tid);  // async DMA under compute
    bf16x8 wf[16];
    const bf16* base = cur + lane32*256;
    #pragma unroll
    for (int t = 0; t < 16; ++t)
      wf[t] = *(const bf16x8*)(base + (((2*t + hi) ^ (lane32 & 31))<<3));
    f32x16 acc = {};
    #pragma unroll
    for (int t = 0; t < 16; ++t)
      acc = __builtin_amdgcn_mfma_f32_32x32x16_bf16(wf[t], B[t], acc, 0, 0, 0);
    epiT<RELU,MASK,ADDT2>(acc, c, row, poly, mk, valid, sAct, sT2, bptr, hi);
    __syncthreads();                     // chunk c+1 staged AND compute c done
  }
}

// pool 20 mask-zeroed rows per polyline -> sPool rows 0..11 (swizzled)
__device__ __forceinline__ void poolT(const bf16* sAct, bf16* sPool, int tid){
  if (tid < 384){
    int poly = tid >> 5, c = tid & 31;
    float m[8];
    bf16x8 v0 = *(const bf16x8*)&sAct[AADDR(poly*20, c)];
    #pragma unroll
    for (int j = 0; j < 8; ++j) m[j] = b2f(v0[j]);
    for (int r = 1; r < 20; ++r){
      bf16x8 v = *(const bf16x8*)&sAct[AADDR(poly*20 + r, c)];
      #pragma unroll
      for (int j = 0; j < 8; ++j) m[j] = fmaxf(m[j], b2f(v[j]));
    }
    bf16x8 o;
    #pragma unroll
    for (int j = 0; j < 8; ++j) o[j] = f2b(m[j]);
    *(bf16x8*)&sPool[AADDR(poly, c)] = o;
  }
}

__global__ __launch_bounds__(512) __attribute__((amdgpu_waves_per_eu(2, 2)))
void traj_kernel(const float* __restrict__ poly, const int* __restrict__ maskp,
                 const float* pre_b0, const float* pre_b1, const float* pre_bias2,
                 const float* mlp_b0, const float* mlp_b1, const float* mlp_bias2,
                 const float* out_b0, const float* out_b1,
                 const bf16* __restrict__ ws,
                 float* __restrict__ outp)
{
  extern __shared__ char smem[];
  bf16*  sAct   = (bf16*)(smem + OFF_ACT);
  bf16*  wb0    = (bf16*)(smem + OFF_WB0);
  bf16*  wb1    = (bf16*)(smem + OFF_WB1);
  bf16*  sT2    = (bf16*)(smem + OFF_T2);
  float* sValid = (float*)(smem + OFF_VAL);
  bf16*  sPool  = wb0;                       // pooled tile aliases wb0 (barrier-separated)
  bf16*  sY     = sAct;                      // y tile aliases sAct (dead after pool2)

  const int tid = threadIdx.x;
  const int w = tid >> 6, L = tid & 63, lane32 = L & 31, hi = L >> 5;
  const int row  = w*32 + lane32;            // 0..255; valid < 240
  const int rowc = row < NROW ? row : NROW - 1;
  const int blk = blockIdx.x;

  const bf16* pw0 = ws + WS_PRE_W0;
  const bf16* pw1 = ws + WS_PRE_W1;
  const bf16* pw2 = ws + WS_PRE_W2;
  const bf16* mw0 = ws + WS_MLP_W0;
  const bf16* mw1 = ws + WS_MLP_W1;
  const bf16* mw2 = ws + WS_MLP_W2;
  const bf16* ow0 = ws + WS_OUT_W0;
  const bf16* ow1 = ws + WS_OUT_W1;

  // ---- phase 0: input (240x32 fp32 -> bf16, swizzled; OOB rows zero) ----
  #pragma unroll
  for (int i = 0; i < 2; ++i){
    int id = tid + 512*i;
    if (id < 960){
      int r = id >> 2, c = id & 3;
      int grow = blk*NROW + r;
      bf16x8 v = {};
      if (grow < TOTROW) v = ld8f(poly + (size_t)grow*32 + c*8, 1.0f);
      *(bf16x8*)&sAct[AADDR(r, c)] = v;
    }
  }
  __syncthreads();
  if (tid < NPOLYB){
    float v = 0.0f;
    #pragma unroll
    for (int r = 0; r < 20; ++r){
      int g = blk*NROW + tid*20 + r;
      if (g < TOTROW && maskp[g]) v = 1.0f;
    }
    sValid[tid] = v;                         // consumed in out1 (after several barriers)
  }

  // ---- pre0: K=32, transposed, W direct from ws (tiny) ----
  {
    bf16x8 B0 = *(const bf16x8*)&sAct[AADDR(rowc, hi)];
    bf16x8 B1 = *(const bf16x8*)&sAct[AADDR(rowc, 2 + hi)];
    #pragma unroll 1
    for (int nt = 0; nt < 8; ++nt){
      const bf16* p = pw0 + (size_t)(nt*32 + lane32)*32 + 8*hi;
      bf16x8 w0 = *(const bf16x8*)p;
      bf16x8 w1 = *(const bf16x8*)(p + 16);
      f32x16 acc = {};
      acc = __builtin_amdgcn_mfma_f32_32x32x16_bf16(w0, B0, acc, 0, 0, 0);
      acc = __builtin_amdgcn_mfma_f32_32x32x16_bf16(w1, B1, acc, 0, 0, 0);
      epiT<1,0,0>(acc, nt, row, 0, 1.0f, row < NROW, sAct, sT2, pre_b0, hi);
    }
  }
  __syncthreads();      // pre0 done; wb buffers free for pre1 staging

  // ---- pre1, pre2 (async dbuf) ----
  layerT<1,0,0>(sAct, wb0, wb1, sT2, pw1, 256, pre_b1,    maskp, blk, row, rowc, lane32, hi, tid);
  layerT<0,1,0>(sAct, wb0, wb1, sT2, pw2, 256, pre_bias2, maskp, blk, row, rowc, lane32, hi, tid);

  // last layer barrier done: all pre2 writes visible
  poolT(sAct, sPool, tid);
  __syncthreads();                    // pool1 visible

  // ---- t2 = pooled @ mlp_w0'[:,256:]^T : wave w handles nt = w (direct global) ----
  {
    bf16x8 Bp[16];
    #pragma unroll
    for (int t = 0; t < 16; ++t)
      Bp[t] = *(const bf16x8*)&sPool[AADDR((lane32 < NPOLYB ? lane32 : 0), 2*t + hi)];
    int nt = w;
    const bf16* p = mw0 + (size_t)(nt*32 + lane32)*512 + 256 + 8*hi;
    f32x16 acc = {};
    #pragma unroll
    for (int t = 0; t < 16; ++t){
      bf16x8 wf = *(const bf16x8*)(p + 16*t);
      acc = __builtin_amdgcn_mfma_f32_32x32x16_bf16(wf, Bp[t], acc, 0, 0, 0);
    }
    if (lane32 < NPOLYB){
      #pragma unroll
      for (int q2 = 0; q2 < 4; ++q2){
        int f0 = nt*32 + 8*q2 + 4*hi;
        bf16x4 o;
        #pragma unroll
        for (int j = 0; j < 4; ++j) o[j] = f2b(acc[4*q2 + j]);
        *(bf16x4*)&sT2[lane32*256 + f0] = o;
      }
    }
  }
  __syncthreads();                    // sT2 ready; sPool(wb0) reads done

  // ---- mlp0 (x-half + t2), mlp1, mlp2 (async dbuf) ----
  layerT<1,0,1>(sAct, wb0, wb1, sT2, mw0, 512, mlp_b0,    maskp, blk, row, rowc, lane32, hi, tid);
  layerT<1,0,0>(sAct, wb0, wb1, sT2, mw1, 256, mlp_b1,    maskp, blk, row, rowc, lane32, hi, tid);
  layerT<0,1,0>(sAct, wb0, wb1, sT2, mw2, 256, mlp_bias2, maskp, blk, row, rowc, lane32, hi, tid);

  // last layer barrier done
  poolT(sAct, sPool, tid);
  __syncthreads();                    // pool2 visible; sAct dead -> sY

  // ---- out0: y = relu(pool2 @ ow0^T + b0) -> sY rows 0..11; wave w: nt = w ----
  {
    bf16x8 Bp[16];
    #pragma unroll
    for (int t = 0; t < 16; ++t)
      Bp[t] = *(const bf16x8*)&sPool[AADDR((lane32 < NPOLYB ? lane32 : 0), 2*t + hi)];
    int nt = w;
    const bf16* p = ow0 + (size_t)(nt*32 + lane32)*256 + 8*hi;
    f32x16 acc = {};
    #pragma unroll
    for (int t = 0; t < 16; ++t){
      bf16x8 wf = *(const bf16x8*)(p + 16*t);
      acc = __builtin_amdgcn_mfma_f32_32x32x16_bf16(wf, Bp[t], acc, 0, 0, 0);
    }
    if (lane32 < NPOLYB){
      #pragma unroll
      for (int q2 = 0; q2 < 4; ++q2){
        int f0 = nt*32 + 8*q2 + 4*hi;
        f32x4 bb = *(const f32x4*)(out_b0 + f0);
        bf16x4 o;
        #pragma unroll
        for (int j = 0; j < 4; ++j) o[j] = f2b(fmaxf(acc[4*q2 + j] + bb[j], 0.0f));
        *(bf16x4*)&sY[lane32*256 + (((nt*4 + q2) ^ (lane32 & 31))<<3) + 4*hi] = o;
      }
    }
  }
  __syncthreads();                    // y visible

  // ---- out1: z = (y @ ow1^T + b1) * valid -> global fp32; wave w: nt = w ----
  {
    bf16x8 By[16];
    #pragma unroll
    for (int t = 0; t < 16; ++t)
      By[t] = *(const bf16x8*)&sY[AADDR((lane32 < NPOLYB ? lane32 : 0), 2*t + hi)];
    int gp = blk*NPOLYB + lane32;
    float vd = (lane32 < NPOLYB) ? sValid[lane32] : 0.0f;
    int nt = w;
    const bf16* p = ow1 + (size_t)(nt*32 + lane32)*256 + 8*hi;
    f32x16 acc = {};
    #pragma unroll
    for (int t = 0; t < 16; ++t){
      bf16x8 wf = *(const bf16x8*)(p + 16*t);
      acc = __builtin_amdgcn_mfma_f32_32x32x16_bf16(wf, By[t], acc, 0, 0, 0);
    }
    if (lane32 < NPOLYB && gp < NPOLY){
      #pragma unroll
      for (int q2 = 0; q2 < 4; ++q2){
        int f0 = nt*32 + 8*q2 + 4*hi;
        f32x4 bb = *(const f32x4*)(out_b1 + f0);
        f32x4 o;
        #pragma unroll
        for (int j = 0; j < 4; ++j) o[j] = (acc[4*q2 + j] + bb[j]) * vd;
        *(f32x4*)&outp[(size_t)gp*256 + f0] = o;
      }
    }
  }
}

extern "C" void kernel_launch(void* const* d_in, const int* in_sizes, int n_in,
                              void* d_out, int out_size, void* d_ws, size_t ws_size,
                              hipStream_t stream)
{
  const float* poly      = (const float*)d_in[0];
  const int*   maskp     = (const int*)  d_in[1];
  const float* pre_w0    = (const float*)d_in[2];
  const float* pre_g0    = (const float*)d_in[3];
  const float* pre_b0    = (const float*)d_in[4];
  const float* pre_w1    = (const float*)d_in[5];
  const float* pre_g1    = (const float*)d_in[6];
  const float* pre_b1    = (const float*)d_in[7];
  const float* pre_w2    = (const float*)d_in[8];
  const float* pre_bias2 = (const float*)d_in[9];
  const float* mlp_w0    = (const float*)d_in[10];
  const float* mlp_g0    = (const float*)d_in[11];
  const float* mlp_b0    = (const float*)d_in[12];
  const float* mlp_w1    = (const float*)d_in[13];
  const float* mlp_g1    = (const float*)d_in[14];
  const float* mlp_b1    = (const float*)d_in[15];
  const float* mlp_w2    = (const float*)d_in[16];
  const float* mlp_bias2 = (const float*)d_in[17];
  const float* out_w0    = (const float*)d_in[18];
  const float* out_b0    = (const float*)d_in[19];
  const float* out_w1    = (const float*)d_in[20];
  const float* out_b1    = (const float*)d_in[21];

  bf16* ws = (bf16*)d_ws;   // 1,064,960 B of ws used

  (void)hipFuncSetAttribute((const void*)&traj_kernel,
                            hipFuncAttributeMaxDynamicSharedMemorySize, LDS_TOTAL);

  prep_kernel<<<dim3(64, 8), dim3(256), 0, stream>>>(
      pre_w0, pre_w1, pre_w2, mlp_w0, mlp_w1, mlp_w2, out_w0, out_w1,
      pre_g0, pre_g1, mlp_g0, mlp_g1, ws);

  traj_kernel<<<dim3(NBLK), dim3(512), LDS_TOTAL, stream>>>(
      poly, maskp,
      pre_b0, pre_b1, pre_bias2,
      mlp_b0, mlp_b1, mlp_bias2,
      out_b0, out_b1,
      ws, (float*)d_out);
}